// Round 6
// baseline (172.293 us; speedup 1.0000x reference)
//
#include <hip/hip_runtime.h>

#define B_DIM   4096
#define IN_DIM  512
#define OUT_DIM 512
#define KTOT    18432              // IN*36
#define BK      64
#define KSPLIT  8
#define KPER    2304               // KTOT/KSPLIT
#define NT8     36                 // K-tiles per block (KPER/BK)

using f32x4 = __attribute__((ext_vector_type(4))) float;
using s16x8 = __attribute__((ext_vector_type(8))) short;
using u32x4 = __attribute__((ext_vector_type(4))) unsigned int;

__device__ __forceinline__ unsigned int f2bf(float f) {
    unsigned int u = __float_as_uint(f);
    return (u + 0x7FFFu + ((u >> 16) & 1u)) >> 16;
}

__device__ __forceinline__ void glds16(const void* g, void* l) {
    __builtin_amdgcn_global_load_lds(
        (const __attribute__((address_space(1))) unsigned int*)g,
        (__attribute__((address_space(3))) unsigned int*)l,
        16, 0, 0);
}

// Exact np.linspace(-1,1,10) + searchsorted(knots[1:], 'left') + clip, in f64.
__device__ __forceinline__ uint2 spline_rec_packed(float xv) {
    float xc = fminf(fmaxf(xv, -1.0f), 1.0f);
    double xd = (double)xc;
    int s = 0;
#pragma unroll
    for (int k = 1; k <= 8; ++k)
        s += ((-1.0 + (double)k * (2.0 / 9.0)) < xd) ? 1 : 0;
    double lo = -1.0 + (double)s * (2.0 / 9.0);
    double hi = -1.0 + (double)(s + 1) * (2.0 / 9.0);
    float t  = (float)((xd - lo) / (hi - lo));
    float t2 = t * t, t3 = t2 * t;
    uint2 r;
    r.x = f2bf(t)  | (f2bf(t2) << 16);
    r.y = f2bf(t3) | ((unsigned int)s << 16);
    return r;
}

// Prepass 1: per (b,i) packed tpow+seg record (8B), layout [B][IN]
__global__ void prep_x_kernel(const float* __restrict__ x, uint2* __restrict__ tp) {
    int idx = blockIdx.x * 256 + threadIdx.x;
    if (idx >= B_DIM * IN_DIM) return;
    tp[idx] = spline_rec_packed(x[idx]);
}

// Prepass 2: coeff -> bf16 (scale folded), TILE-IMAGE order:
// [nt(2)][kt(288)][oct(8)][row(256)][8 bf16] so glds-linear == LDS image.
__global__ void prep_coeff2(const float* __restrict__ c,
                            const float* __restrict__ scale,
                            u32x4* __restrict__ cbf2) {
    int g = blockIdx.x * 256 + threadIdx.x;        // one per 16B granule
    if (g >= (OUT_DIM * KTOT) / 8) return;
    int row = g & 255;
    int oct = (g >> 8) & 7;
    int hi  = g >> 11;                             // nt*288 + kt, 0..575
    int ntg = hi >= 288 ? 1 : 0;
    int kt  = hi - ntg * 288;
    int j = ntg * 256 + row;
    int k = kt * 64 + oct * 8;
    float s = scale[j];
    const float* src = c + (size_t)j * KTOT + k;
    f32x4 a = *(const f32x4*)src;
    f32x4 b = *(const f32x4*)(src + 4);
    u32x4 o;
    o.x = f2bf(a.x * s) | (f2bf(a.y * s) << 16);
    o.y = f2bf(a.z * s) | (f2bf(a.w * s) << 16);
    o.z = f2bf(b.x * s) | (f2bf(b.y * s) << 16);
    o.w = f2bf(b.z * s) | (f2bf(b.w * s) << 16);
    cbf2[g] = o;
}

// scatter 3 candidate records into the staging A tile (own 32-elem half only)
__device__ __forceinline__ void scat3(char* Aq, int ar, int ah,
                                      uint2 q0, uint2 q1, uint2 q2,
                                      int ifirst, int k0) {
#pragma unroll
    for (int cc = 0; cc < 3; ++cc) {
        uint2 rec = cc == 0 ? q0 : (cc == 1 ? q1 : q2);
        int i = ifirst + cc;
        if (i < IN_DIM) {
            int s = (int)(rec.y >> 16);
            int off = i * 36 + s * 4 - k0;                 // multiple of 4; never straddles
            if (off >= 0 && off < 64 && ((off >> 5) == ah)) {
                uint2 w;
                w.x = 0x3F80u | (rec.x << 16);             // {1, t}
                w.y = (rec.x >> 16) | (rec.y << 16);       // {t2, t3}
                *(uint2*)(Aq + (off >> 3) * 4096 + ar * 16 + (off & 4) * 2) = w;
            }
        }
    }
}

#define BAR()   __builtin_amdgcn_s_barrier()
#define SB0()   __builtin_amdgcn_sched_barrier(0)
#define WLGKM() asm volatile("s_waitcnt lgkmcnt(0)" ::: "memory")
#define WVM0()  asm volatile("s_waitcnt vmcnt(0)"   ::: "memory")

// 256x256 tile, 8 waves (2Mx4N), BK=64, dbuf LDS 128KB, 4 phases/K-tile.
// Round-3 structure; FIX: MFMA accumulator indexed by M-HALF (0,1,0,1), not phase.
__launch_bounds__(512, 2)
__global__ void kan_gemm8(const unsigned short* __restrict__ cbf2,
                          const uint2* __restrict__ tp,
                          float* __restrict__ out) {
    __shared__ u32x4 ldsRaw[131072 / 16];          // A: [2][8][256][16B], B: +64KB
    char* lds = (char*)ldsRaw;

    const int tid  = threadIdx.x;
    const int lane = tid & 63;
    const int wave = tid >> 6;
    const int wm = wave >> 2, wn = wave & 3;
    const int l15 = lane & 15, lhi = lane >> 4;

    const int bid = blockIdx.x;                    // = ks*32 + mt*2 + nt
    const int ks = bid >> 5;
    const int mt = (bid >> 1) & 15;
    const int nt = bid & 1;
    const int m0g = mt * 256, n0g = nt * 256;
    const int kbase = ks * KPER;

    const int ar = tid & 255, ah = tid >> 8;       // staging row / oct-half

    const uint2* tpRow = tp + (size_t)(m0g + ar) * IN_DIM;
    const char*  cbase = (const char*)cbf2 + (size_t)(nt * 288 + ks * NT8) * 32768;

    const int aoff = (wm * 128 + l15) * 16;        // A frag row byte offset
    const int boff = (wn * 64  + l15) * 16;        // B frag row byte offset
    const int ohi  = lhi * 4096;

    f32x4 acc[8][4] = {};
    s16x8 av[4], bv[4];
    uint2 r0, r1, r2;

    // ---------------- prologue: build tile 0 in buf0 ----------------
    {
        char* A0 = lds;
        char* B0 = lds + 65536;
        const int if0 = kbase / 36;
        r0 = tpRow[if0];
        r1 = tpRow[if0 + 1 < IN_DIM ? if0 + 1 : IN_DIM - 1];
        r2 = tpRow[if0 + 2 < IN_DIM ? if0 + 2 : IN_DIM - 1];
        u32x4 z = {};
#pragma unroll
        for (int zi = 0; zi < 4; ++zi)
            *(u32x4*)(A0 + (ah * 4 + zi) * 4096 + ar * 16) = z;
        scat3(A0, ar, ah, r0, r1, r2, if0, kbase);
#pragma unroll
        for (int it = 0; it < 4; ++it)
            glds16(cbase + it * 8192 + tid * 16, B0 + it * 8192 + tid * 16);
        WVM0();
        const int if1 = (kbase + BK) / 36;         // records for tile 1's scatter
        r0 = tpRow[if1];
        r1 = tpRow[if1 + 1 < IN_DIM ? if1 + 1 : IN_DIM - 1];
        r2 = tpRow[if1 + 2 < IN_DIM ? if1 + 2 : IN_DIM - 1];
        WLGKM();
        BAR();
        SB0();
    }

#define LOAD_A(KH, MH)                                                          \
    _Pragma("unroll") for (int c_ = 0; c_ < 4; ++c_)                            \
        av[c_] = *(const s16x8*)(Ap + (KH) * 16384 + ohi + aoff + ((MH) * 4 + c_) * 256);
#define LOAD_B(KH)                                                              \
    _Pragma("unroll") for (int c_ = 0; c_ < 4; ++c_)                            \
        bv[c_] = *(const s16x8*)(Bp + (KH) * 16384 + ohi + boff + c_ * 256);
#define MFMA_Q(MH)                                                              \
    _Pragma("unroll") for (int mf_ = 0; mf_ < 4; ++mf_)                         \
        _Pragma("unroll") for (int nf_ = 0; nf_ < 4; ++nf_)                     \
            acc[(MH) * 4 + mf_][nf_] = __builtin_amdgcn_mfma_f32_16x16x32_bf16( \
                av[mf_], bv[nf_], acc[(MH) * 4 + mf_][nf_], 0, 0, 0);
#define PHASE_MID() BAR(); WLGKM(); SB0(); __builtin_amdgcn_s_setprio(1)
#define PHASE_END() __builtin_amdgcn_s_setprio(0); BAR(); SB0()

    for (int t = 0; t < NT8; ++t) {
        const int p = t & 1;
        const char* Ap = lds + p * 32768;
        const char* Bp = lds + 65536 + p * 32768;
        char* Aq = lds + (p ^ 1) * 32768;
        char* Bq = lds + 65536 + (p ^ 1) * 32768;
        const int tt1 = t + 1 < NT8 ? t + 1 : NT8 - 1;
        const int k0n = kbase + tt1 * BK;
        const char* srcT = cbase + (size_t)tt1 * 32768;
        u32x4 z = {};

        // ---- phase 0: kh0, m-half 0 ----
        LOAD_B(0); LOAD_A(0, 0);
        *(u32x4*)(Aq + (ah * 4 + 0) * 4096 + ar * 16) = z;
        glds16(srcT + 0 * 8192 + tid * 16, Bq + 0 * 8192 + tid * 16);
        PHASE_MID(); MFMA_Q(0); PHASE_END();

        // ---- phase 1: kh0, m-half 1 ----
        LOAD_A(0, 1);
        *(u32x4*)(Aq + (ah * 4 + 1) * 4096 + ar * 16) = z;
        glds16(srcT + 1 * 8192 + tid * 16, Bq + 1 * 8192 + tid * 16);
        PHASE_MID(); MFMA_Q(1); PHASE_END();

        // ---- phase 2: kh1, m-half 0 (accumulates into acc[0..3] again) ----
        LOAD_B(1); LOAD_A(1, 0);
        *(u32x4*)(Aq + (ah * 4 + 2) * 4096 + ar * 16) = z;
        glds16(srcT + 2 * 8192 + tid * 16, Bq + 2 * 8192 + tid * 16);
        PHASE_MID(); MFMA_Q(0); PHASE_END();

        // ---- phase 3: kh1, m-half 1 + scatter + drain + rec prefetch ----
        LOAD_A(1, 1);
        *(u32x4*)(Aq + (ah * 4 + 3) * 4096 + ar * 16) = z;
        {
            const int if1 = k0n / 36;
            scat3(Aq, ar, ah, r0, r1, r2, if1, k0n);   // all own octets zeroed by now
        }
        glds16(srcT + 3 * 8192 + tid * 16, Bq + 3 * 8192 + tid * 16);
        WVM0();                                        // drain B(t+1) glds before buf swap
        {
            const int tt2 = t + 2 < NT8 ? t + 2 : NT8 - 1;
            const int if2 = (kbase + tt2 * BK) / 36;   // prefetch recs for next scatter
            r0 = tpRow[if2];
            r1 = tpRow[if2 + 1 < IN_DIM ? if2 + 1 : IN_DIM - 1];
            r2 = tpRow[if2 + 2 < IN_DIM ? if2 + 2 : IN_DIM - 1];
        }
        PHASE_MID(); MFMA_Q(1); PHASE_END();
    }

    // ---- epilogue: split-K atomics. C/D: col=lane&15 (n), row=(lane>>4)*4+e (m) ----
#pragma unroll
    for (int mf = 0; mf < 8; ++mf) {
        const int rg = m0g + wm * 128 + mf * 16 + lhi * 4;
#pragma unroll
        for (int nf = 0; nf < 4; ++nf) {
            const int cg = n0g + wn * 64 + nf * 16 + l15;
#pragma unroll
            for (int e = 0; e < 4; ++e)
                atomicAdd(out + (size_t)(rg + e) * OUT_DIM + cg, acc[mf][nf][e]);
        }
    }
}

// ---------------- fallback (no workspace): round-1 proven kernel ----------------
#define BM 128
#define BN 128
#define FBK 64
#define FKPER  4608
#define FSTEPS 72
__launch_bounds__(256, 2)
__global__ void kan_gemm_ref(const float* __restrict__ x,
                             const float* __restrict__ coeff,
                             const float* __restrict__ scale,
                             float* __restrict__ out) {
    __shared__ unsigned short AsF[BM * 72];
    __shared__ unsigned short BsF[8 * BN * 8];
    const int tid  = threadIdx.x;
    const int lane = tid & 63;
    const int wave = tid >> 6;
    const int wm = wave >> 1, wn = wave & 1;
    const int l15 = lane & 15, lhi = lane >> 4;
    const int bid = blockIdx.x;
    const int nt = bid & 3;
    const int ks = (bid >> 2) & 3;
    const int mt = bid >> 4;
    const int m0g = mt * BM, n0g = nt * BN, kbase = ks * FKPER;
    const int ar = tid >> 1, ah = tid & 1;
    const int abrow = m0g + ar;
    const int bjg = n0g + (tid & 127);
    const float bscale = scale[bjg];
    char* AsB = (char*)AsF;
    char* BsB = (char*)BsF;
    f32x4 acc[4][4] = {};
    for (int step = 0; step < FSTEPS; ++step) {
        const int k0 = kbase + step * FBK;
        {
            char* rb = AsB + ar * 144;
            u32x4 z = {};
            if (ah == 0) {
#pragma unroll
                for (int z4 = 0; z4 < 4; ++z4) *(u32x4*)(rb + z4 * 16) = z;
            } else {
#pragma unroll
                for (int z4 = 4; z4 < 9; ++z4) *(u32x4*)(rb + z4 * 16) = z;
            }
            const int ifirst = k0 / 36;
#pragma unroll
            for (int ii = 0; ii < 2; ++ii) {
                const int cand = ah + ii * 2;
                const int i = ifirst + cand;
                if (cand < 3 && i * 36 < k0 + FBK && i < IN_DIM) {
                    uint2 rec = spline_rec_packed(x[(size_t)abrow * IN_DIM + i]);
                    int s = (int)(rec.y >> 16);
                    const int off = i * 36 + s * 4 - k0;
                    unsigned int w0 = 0x3F80u | (rec.x << 16);
                    unsigned int w1 = (rec.x >> 16) | (rec.y << 16);
                    if (off >= 0 && off <= 62) *(unsigned int*)(rb + off * 2) = w0;
                    const int off2 = off + 2;
                    if (off2 >= 0 && off2 <= 62) *(unsigned int*)(rb + off2 * 2) = w1;
                }
            }
        }
#pragma unroll
        for (int it = 0; it < 4; ++it) {
            const int q  = it * 256 + tid;
            const int c  = q >> 7;
            const int kk = k0 + c * 8;
            f32x4 a = *(const f32x4*)(coeff + (size_t)bjg * KTOT + kk);
            f32x4 b = *(const f32x4*)(coeff + (size_t)bjg * KTOT + kk + 4);
            u32x4 o;
            o.x = f2bf(a.x * bscale) | (f2bf(a.y * bscale) << 16);
            o.y = f2bf(a.z * bscale) | (f2bf(a.w * bscale) << 16);
            o.z = f2bf(b.x * bscale) | (f2bf(b.y * bscale) << 16);
            o.w = f2bf(b.z * bscale) | (f2bf(b.w * bscale) << 16);
            *(u32x4*)(BsB + q * 16) = o;
        }
        __syncthreads();
#pragma unroll
        for (int kh = 0; kh < 2; ++kh) {
            const int kk = kh * 32;
            s16x8 a[4], b[4];
#pragma unroll
            for (int mf = 0; mf < 4; ++mf)
                a[mf] = *(const s16x8*)(AsB + (wm * 64 + mf * 16 + l15) * 144 + (kk + lhi * 8) * 2);
#pragma unroll
            for (int nf = 0; nf < 4; ++nf)
                b[nf] = *(const s16x8*)(BsB + (kh * 4 + lhi) * 2048 + (wn * 64 + nf * 16 + l15) * 16);
#pragma unroll
            for (int mf = 0; mf < 4; ++mf)
#pragma unroll
                for (int nf = 0; nf < 4; ++nf)
                    acc[mf][nf] = __builtin_amdgcn_mfma_f32_16x16x32_bf16(a[mf], b[nf], acc[mf][nf], 0, 0, 0);
        }
        __syncthreads();
    }
#pragma unroll
    for (int mf = 0; mf < 4; ++mf) {
        const int cmBase = m0g + wm * 64 + mf * 16 + lhi * 4;
#pragma unroll
        for (int nf = 0; nf < 4; ++nf) {
            const int cn = n0g + wn * 64 + nf * 16 + l15;
#pragma unroll
            for (int e = 0; e < 4; ++e)
                atomicAdd(out + (size_t)(cmBase + e) * OUT_DIM + cn, acc[mf][nf][e]);
        }
    }
}

extern "C" void kernel_launch(void* const* d_in, const int* in_sizes, int n_in,
                              void* d_out, int out_size, void* d_ws, size_t ws_size,
                              hipStream_t stream) {
    const float* x     = (const float*)d_in[0];
    const float* coeff = (const float*)d_in[1];
    const float* scale = (const float*)d_in[2];
    float* out = (float*)d_out;

    const size_t SZ_CBF = (size_t)OUT_DIM * KTOT * 2;   // 18,874,368
    const size_t SZ_TP  = (size_t)B_DIM * IN_DIM * 8;   // 16,777,216
    const size_t NEED   = SZ_CBF + SZ_TP;               // ~35.7 MB

    hipMemsetAsync(d_out, 0, (size_t)B_DIM * OUT_DIM * sizeof(float), stream);

    if (ws_size >= NEED) {
        unsigned short* cbf2 = (unsigned short*)d_ws;
        uint2*          tp   = (uint2*)((char*)d_ws + SZ_CBF);
        prep_coeff2<<<4608, 256, 0, stream>>>(coeff, scale, (u32x4*)cbf2);
        prep_x_kernel<<<8192, 256, 0, stream>>>(x, tp);
        kan_gemm8<<<256, 512, 0, stream>>>(cbf2, tp, out);
    } else {
        kan_gemm_ref<<<512, 256, 0, stream>>>(x, coeff, scale, out);
    }
}

// Round 7
// 168.834 us; speedup vs baseline: 1.0205x; 1.0205x over previous
//
#include <hip/hip_runtime.h>

#define B_DIM   4096
#define IN_DIM  512
#define OUT_DIM 512
#define KTOT    18432              // IN*36
#define BK      64
#define KSPLIT  8
#define KPER    2304               // KTOT/KSPLIT
#define NT8     36                 // K-tiles per block (KPER/BK)

using f32x4 = __attribute__((ext_vector_type(4))) float;
using s16x8 = __attribute__((ext_vector_type(8))) short;
using u32x4 = __attribute__((ext_vector_type(4))) unsigned int;

__device__ __forceinline__ unsigned int f2bf(float f) {
    unsigned int u = __float_as_uint(f);
    return (u + 0x7FFFu + ((u >> 16) & 1u)) >> 16;
}

__device__ __forceinline__ void glds16(const void* g, void* l) {
    __builtin_amdgcn_global_load_lds(
        (const __attribute__((address_space(1))) unsigned int*)g,
        (__attribute__((address_space(3))) unsigned int*)l,
        16, 0, 0);
}

// Exact np.linspace(-1,1,10) + searchsorted(knots[1:], 'left') + clip, in f64.
__device__ __forceinline__ uint2 spline_rec_packed(float xv) {
    float xc = fminf(fmaxf(xv, -1.0f), 1.0f);
    double xd = (double)xc;
    int s = 0;
#pragma unroll
    for (int k = 1; k <= 8; ++k)
        s += ((-1.0 + (double)k * (2.0 / 9.0)) < xd) ? 1 : 0;
    double lo = -1.0 + (double)s * (2.0 / 9.0);
    double hi = -1.0 + (double)(s + 1) * (2.0 / 9.0);
    float t  = (float)((xd - lo) / (hi - lo));
    float t2 = t * t, t3 = t2 * t;
    uint2 r;
    r.x = f2bf(t)  | (f2bf(t2) << 16);
    r.y = f2bf(t3) | ((unsigned int)s << 16);
    return r;
}

// Prepass 1: per (b,i) packed tpow+seg record (8B), layout [B][IN]
__global__ void prep_x_kernel(const float* __restrict__ x, uint2* __restrict__ tp) {
    int idx = blockIdx.x * 256 + threadIdx.x;
    if (idx >= B_DIM * IN_DIM) return;
    tp[idx] = spline_rec_packed(x[idx]);
}

// Prepass 2: coeff -> bf16 (scale folded), TILE-IMAGE order:
// [nt(2)][kt(288)][oct(8)][row(256)][8 bf16] so glds-linear == LDS image.
__global__ void prep_coeff2(const float* __restrict__ c,
                            const float* __restrict__ scale,
                            u32x4* __restrict__ cbf2) {
    int g = blockIdx.x * 256 + threadIdx.x;        // one per 16B granule
    if (g >= (OUT_DIM * KTOT) / 8) return;
    int row = g & 255;
    int oct = (g >> 8) & 7;
    int hi  = g >> 11;                             // nt*288 + kt, 0..575
    int ntg = hi >= 288 ? 1 : 0;
    int kt  = hi - ntg * 288;
    int j = ntg * 256 + row;
    int k = kt * 64 + oct * 8;
    float s = scale[j];
    const float* src = c + (size_t)j * KTOT + k;
    f32x4 a = *(const f32x4*)src;
    f32x4 b = *(const f32x4*)(src + 4);
    u32x4 o;
    o.x = f2bf(a.x * s) | (f2bf(a.y * s) << 16);
    o.y = f2bf(a.z * s) | (f2bf(a.w * s) << 16);
    o.z = f2bf(b.x * s) | (f2bf(b.y * s) << 16);
    o.w = f2bf(b.z * s) | (f2bf(b.w * s) << 16);
    cbf2[g] = o;
}

// scatter 3 candidate records into the staging A tile (own 32-elem half only)
__device__ __forceinline__ void scat3(char* Aq, int ar, int ah,
                                      uint2 q0, uint2 q1, uint2 q2,
                                      int ifirst, int k0) {
#pragma unroll
    for (int cc = 0; cc < 3; ++cc) {
        uint2 rec = cc == 0 ? q0 : (cc == 1 ? q1 : q2);
        int i = ifirst + cc;
        if (i < IN_DIM) {
            int s = (int)(rec.y >> 16);
            int off = i * 36 + s * 4 - k0;                 // multiple of 4; never straddles
            if (off >= 0 && off < 64 && ((off >> 5) == ah)) {
                uint2 w;
                w.x = 0x3F80u | (rec.x << 16);             // {1, t}
                w.y = (rec.x >> 16) | (rec.y << 16);       // {t2, t3}
                *(uint2*)(Aq + (off >> 3) * 4096 + ar * 16 + (off & 4) * 2) = w;
            }
        }
    }
}

#define BAR()   __builtin_amdgcn_s_barrier()
#define SB0()   __builtin_amdgcn_sched_barrier(0)
#define WLGKM() asm volatile("s_waitcnt lgkmcnt(0)" ::: "memory")
#define WVM0()  asm volatile("s_waitcnt vmcnt(0)"   ::: "memory")

// 256x256 tile, 8 waves (2Mx4N), BK=64, dbuf LDS 128KB, 4 phases/K-tile.
// R7: glds+zeroes front-loaded into phases 0-1 so the ph3 vmcnt(0) waits on
// loads >=2 phases old; tp-prefetch issued AFTER the drain (stays in flight).
__launch_bounds__(512, 2)
__global__ void kan_gemm8(const unsigned short* __restrict__ cbf2,
                          const uint2* __restrict__ tp,
                          float* __restrict__ out) {
    __shared__ u32x4 ldsRaw[131072 / 16];          // A: [2][8][256][16B], B: +64KB
    char* lds = (char*)ldsRaw;

    const int tid  = threadIdx.x;
    const int lane = tid & 63;
    const int wave = tid >> 6;
    const int wm = wave >> 2, wn = wave & 3;
    const int l15 = lane & 15, lhi = lane >> 4;

    const int bid = blockIdx.x;                    // = mt*16 + ks*2 + nt
    const int mt = bid >> 4;                       // XCD = (2ks+nt)%8: one B panel
    const int ks = (bid >> 1) & 7;                 // per XCD -> L2-resident B
    const int nt = bid & 1;
    const int m0g = mt * 256, n0g = nt * 256;
    const int kbase = ks * KPER;

    const int ar = tid & 255, ah = tid >> 8;       // staging row / oct-half

    const uint2* tpRow = tp + (size_t)(m0g + ar) * IN_DIM;
    const char*  cbase = (const char*)cbf2 + (size_t)(nt * 288 + ks * NT8) * 32768;

    const int aoff = (wm * 128 + l15) * 16;        // A frag row byte offset
    const int boff = (wn * 64  + l15) * 16;        // B frag row byte offset
    const int ohi  = lhi * 4096;

    f32x4 acc[8][4] = {};
    s16x8 av[4], bv[4];
    uint2 r0, r1, r2;

    // ---------------- prologue: build tile 0 in buf0 ----------------
    {
        char* A0 = lds;
        char* B0 = lds + 65536;
        const int if0 = kbase / 36;
        r0 = tpRow[if0];
        r1 = tpRow[if0 + 1 < IN_DIM ? if0 + 1 : IN_DIM - 1];
        r2 = tpRow[if0 + 2 < IN_DIM ? if0 + 2 : IN_DIM - 1];
        u32x4 z = {};
#pragma unroll
        for (int zi = 0; zi < 4; ++zi)
            *(u32x4*)(A0 + (ah * 4 + zi) * 4096 + ar * 16) = z;
        scat3(A0, ar, ah, r0, r1, r2, if0, kbase);
#pragma unroll
        for (int it = 0; it < 4; ++it)
            glds16(cbase + it * 8192 + tid * 16, B0 + it * 8192 + tid * 16);
        WVM0();
        const int if1 = (kbase + BK) / 36;         // records for tile 1's scatter
        r0 = tpRow[if1];
        r1 = tpRow[if1 + 1 < IN_DIM ? if1 + 1 : IN_DIM - 1];
        r2 = tpRow[if1 + 2 < IN_DIM ? if1 + 2 : IN_DIM - 1];
        WLGKM();
        BAR();
        SB0();
    }

#define LOAD_A(KH, MH)                                                          \
    _Pragma("unroll") for (int c_ = 0; c_ < 4; ++c_)                            \
        av[c_] = *(const s16x8*)(Ap + (KH) * 16384 + ohi + aoff + ((MH) * 4 + c_) * 256);
#define LOAD_B(KH)                                                              \
    _Pragma("unroll") for (int c_ = 0; c_ < 4; ++c_)                            \
        bv[c_] = *(const s16x8*)(Bp + (KH) * 16384 + ohi + boff + c_ * 256);
#define MFMA_Q(MH)                                                              \
    _Pragma("unroll") for (int mf_ = 0; mf_ < 4; ++mf_)                         \
        _Pragma("unroll") for (int nf_ = 0; nf_ < 4; ++nf_)                     \
            acc[(MH) * 4 + mf_][nf_] = __builtin_amdgcn_mfma_f32_16x16x32_bf16( \
                av[mf_], bv[nf_], acc[(MH) * 4 + mf_][nf_], 0, 0, 0);
#define PHASE_MID() BAR(); WLGKM(); SB0(); __builtin_amdgcn_s_setprio(1)
#define PHASE_END() __builtin_amdgcn_s_setprio(0); BAR(); SB0()

    for (int t = 0; t < NT8; ++t) {
        const int p = t & 1;
        const char* Ap = lds + p * 32768;
        const char* Bp = lds + 65536 + p * 32768;
        char* Aq = lds + (p ^ 1) * 32768;
        char* Bq = lds + 65536 + (p ^ 1) * 32768;
        const int tt1 = t + 1 < NT8 ? t + 1 : NT8 - 1;
        const int k0n = kbase + tt1 * BK;
        const char* srcT = cbase + (size_t)tt1 * 32768;
        u32x4 z = {};

        // ---- phase 0: kh0, m-half 0; stage: zero oct0-1 + glds 0-1 ----
        LOAD_B(0); LOAD_A(0, 0);
        *(u32x4*)(Aq + (ah * 4 + 0) * 4096 + ar * 16) = z;
        *(u32x4*)(Aq + (ah * 4 + 1) * 4096 + ar * 16) = z;
        glds16(srcT + 0 * 8192 + tid * 16, Bq + 0 * 8192 + tid * 16);
        glds16(srcT + 1 * 8192 + tid * 16, Bq + 1 * 8192 + tid * 16);
        PHASE_MID(); MFMA_Q(0); PHASE_END();

        // ---- phase 1: kh0, m-half 1; stage: zero oct2-3 + glds 2-3 ----
        LOAD_A(0, 1);
        *(u32x4*)(Aq + (ah * 4 + 2) * 4096 + ar * 16) = z;
        *(u32x4*)(Aq + (ah * 4 + 3) * 4096 + ar * 16) = z;
        glds16(srcT + 2 * 8192 + tid * 16, Bq + 2 * 8192 + tid * 16);
        glds16(srcT + 3 * 8192 + tid * 16, Bq + 3 * 8192 + tid * 16);
        PHASE_MID(); MFMA_Q(1); PHASE_END();

        // ---- phase 2: kh1, m-half 0 (no staging) ----
        LOAD_B(1); LOAD_A(1, 0);
        PHASE_MID(); MFMA_Q(0); PHASE_END();

        // ---- phase 3: kh1, m-half 1; scatter + drain(old glds) + tp prefetch ----
        LOAD_A(1, 1);
        {
            const int if1 = k0n / 36;
            scat3(Aq, ar, ah, r0, r1, r2, if1, k0n);   // zeroes drained at ph1/ph2 WLGKM
        }
        WVM0();                                        // glds are >=2 phases old: ~free
        {
            const int tt2 = t + 2 < NT8 ? t + 2 : NT8 - 1;
            const int if2 = (kbase + tt2 * BK) / 36;   // issued AFTER drain: stays in flight
            r0 = tpRow[if2];
            r1 = tpRow[if2 + 1 < IN_DIM ? if2 + 1 : IN_DIM - 1];
            r2 = tpRow[if2 + 2 < IN_DIM ? if2 + 2 : IN_DIM - 1];
        }
        PHASE_MID(); MFMA_Q(1); PHASE_END();
    }

    // ---- epilogue: split-K atomics. C/D: col=lane&15 (n), row=(lane>>4)*4+e (m) ----
#pragma unroll
    for (int mf = 0; mf < 8; ++mf) {
        const int rg = m0g + wm * 128 + mf * 16 + lhi * 4;
#pragma unroll
        for (int nf = 0; nf < 4; ++nf) {
            const int cg = n0g + wn * 64 + nf * 16 + l15;
#pragma unroll
            for (int e = 0; e < 4; ++e)
                atomicAdd(out + (size_t)(rg + e) * OUT_DIM + cg, acc[mf][nf][e]);
        }
    }
}

// ---------------- fallback (no workspace): round-1 proven kernel ----------------
#define BM 128
#define BN 128
#define FBK 64
#define FKPER  4608
#define FSTEPS 72
__launch_bounds__(256, 2)
__global__ void kan_gemm_ref(const float* __restrict__ x,
                             const float* __restrict__ coeff,
                             const float* __restrict__ scale,
                             float* __restrict__ out) {
    __shared__ unsigned short AsF[BM * 72];
    __shared__ unsigned short BsF[8 * BN * 8];
    const int tid  = threadIdx.x;
    const int lane = tid & 63;
    const int wave = tid >> 6;
    const int wm = wave >> 1, wn = wave & 1;
    const int l15 = lane & 15, lhi = lane >> 4;
    const int bid = blockIdx.x;
    const int nt = bid & 3;
    const int ks = (bid >> 2) & 3;
    const int mt = bid >> 4;
    const int m0g = mt * BM, n0g = nt * BN, kbase = ks * FKPER;
    const int ar = tid >> 1, ah = tid & 1;
    const int abrow = m0g + ar;
    const int bjg = n0g + (tid & 127);
    const float bscale = scale[bjg];
    char* AsB = (char*)AsF;
    char* BsB = (char*)BsF;
    f32x4 acc[4][4] = {};
    for (int step = 0; step < FSTEPS; ++step) {
        const int k0 = kbase + step * FBK;
        {
            char* rb = AsB + ar * 144;
            u32x4 z = {};
            if (ah == 0) {
#pragma unroll
                for (int z4 = 0; z4 < 4; ++z4) *(u32x4*)(rb + z4 * 16) = z;
            } else {
#pragma unroll
                for (int z4 = 4; z4 < 9; ++z4) *(u32x4*)(rb + z4 * 16) = z;
            }
            const int ifirst = k0 / 36;
#pragma unroll
            for (int ii = 0; ii < 2; ++ii) {
                const int cand = ah + ii * 2;
                const int i = ifirst + cand;
                if (cand < 3 && i * 36 < k0 + FBK && i < IN_DIM) {
                    uint2 rec = spline_rec_packed(x[(size_t)abrow * IN_DIM + i]);
                    int s = (int)(rec.y >> 16);
                    const int off = i * 36 + s * 4 - k0;
                    unsigned int w0 = 0x3F80u | (rec.x << 16);
                    unsigned int w1 = (rec.x >> 16) | (rec.y << 16);
                    if (off >= 0 && off <= 62) *(unsigned int*)(rb + off * 2) = w0;
                    const int off2 = off + 2;
                    if (off2 >= 0 && off2 <= 62) *(unsigned int*)(rb + off2 * 2) = w1;
                }
            }
        }
#pragma unroll
        for (int it = 0; it < 4; ++it) {
            const int q  = it * 256 + tid;
            const int c  = q >> 7;
            const int kk = k0 + c * 8;
            f32x4 a = *(const f32x4*)(coeff + (size_t)bjg * KTOT + kk);
            f32x4 b = *(const f32x4*)(coeff + (size_t)bjg * KTOT + kk + 4);
            u32x4 o;
            o.x = f2bf(a.x * bscale) | (f2bf(a.y * bscale) << 16);
            o.y = f2bf(a.z * bscale) | (f2bf(a.w * bscale) << 16);
            o.z = f2bf(b.x * bscale) | (f2bf(b.y * bscale) << 16);
            o.w = f2bf(b.z * bscale) | (f2bf(b.w * bscale) << 16);
            *(u32x4*)(BsB + q * 16) = o;
        }
        __syncthreads();
#pragma unroll
        for (int kh = 0; kh < 2; ++kh) {
            const int kk = kh * 32;
            s16x8 a[4], b[4];
#pragma unroll
            for (int mf = 0; mf < 4; ++mf)
                a[mf] = *(const s16x8*)(AsB + (wm * 64 + mf * 16 + l15) * 144 + (kk + lhi * 8) * 2);
#pragma unroll
            for (int nf = 0; nf < 4; ++nf)
                b[nf] = *(const s16x8*)(BsB + (kh * 4 + lhi) * 2048 + (wn * 64 + nf * 16 + l15) * 16);
#pragma unroll
            for (int mf = 0; mf < 4; ++mf)
#pragma unroll
                for (int nf = 0; nf < 4; ++nf)
                    acc[mf][nf] = __builtin_amdgcn_mfma_f32_16x16x32_bf16(a[mf], b[nf], acc[mf][nf], 0, 0, 0);
        }
        __syncthreads();
    }
#pragma unroll
    for (int mf = 0; mf < 4; ++mf) {
        const int cmBase = m0g + wm * 64 + mf * 16 + lhi * 4;
#pragma unroll
        for (int nf = 0; nf < 4; ++nf) {
            const int cn = n0g + wn * 64 + nf * 16 + l15;
#pragma unroll
            for (int e = 0; e < 4; ++e)
                atomicAdd(out + (size_t)(cmBase + e) * OUT_DIM + cn, acc[mf][nf][e]);
        }
    }
}

extern "C" void kernel_launch(void* const* d_in, const int* in_sizes, int n_in,
                              void* d_out, int out_size, void* d_ws, size_t ws_size,
                              hipStream_t stream) {
    const float* x     = (const float*)d_in[0];
    const float* coeff = (const float*)d_in[1];
    const float* scale = (const float*)d_in[2];
    float* out = (float*)d_out;

    const size_t SZ_CBF = (size_t)OUT_DIM * KTOT * 2;   // 18,874,368
    const size_t SZ_TP  = (size_t)B_DIM * IN_DIM * 8;   // 16,777,216
    const size_t NEED   = SZ_CBF + SZ_TP;               // ~35.7 MB

    hipMemsetAsync(d_out, 0, (size_t)B_DIM * OUT_DIM * sizeof(float), stream);

    if (ws_size >= NEED) {
        unsigned short* cbf2 = (unsigned short*)d_ws;
        uint2*          tp   = (uint2*)((char*)d_ws + SZ_CBF);
        prep_coeff2<<<4608, 256, 0, stream>>>(coeff, scale, (u32x4*)cbf2);
        prep_x_kernel<<<8192, 256, 0, stream>>>(x, tp);
        kan_gemm8<<<256, 512, 0, stream>>>(cbf2, tp, out);
    } else {
        kan_gemm_ref<<<512, 256, 0, stream>>>(x, coeff, scale, out);
    }
}

// Round 8
// 165.491 us; speedup vs baseline: 1.0411x; 1.0202x over previous
//
#include <hip/hip_runtime.h>

#define B_DIM   4096
#define IN_DIM  512
#define OUT_DIM 512
#define KTOT    18432              // IN*36
#define BK      64
#define KSPLIT  8
#define KPER    2304               // KTOT/KSPLIT
#define NT8     36                 // K-tiles per block (KPER/BK)

using f32x4 = __attribute__((ext_vector_type(4))) float;
using s16x8 = __attribute__((ext_vector_type(8))) short;
using u32x4 = __attribute__((ext_vector_type(4))) unsigned int;

__device__ __forceinline__ unsigned int f2bf(float f) {
    unsigned int u = __float_as_uint(f);
    return (u + 0x7FFFu + ((u >> 16) & 1u)) >> 16;
}

__device__ __forceinline__ void glds16(const void* g, void* l) {
    __builtin_amdgcn_global_load_lds(
        (const __attribute__((address_space(1))) unsigned int*)g,
        (__attribute__((address_space(3))) unsigned int*)l,
        16, 0, 0);
}

// Exact np.linspace(-1,1,10) + searchsorted(knots[1:], 'left') + clip, in f64.
__device__ __forceinline__ uint2 spline_rec_packed(float xv) {
    float xc = fminf(fmaxf(xv, -1.0f), 1.0f);
    double xd = (double)xc;
    int s = 0;
#pragma unroll
    for (int k = 1; k <= 8; ++k)
        s += ((-1.0 + (double)k * (2.0 / 9.0)) < xd) ? 1 : 0;
    double lo = -1.0 + (double)s * (2.0 / 9.0);
    double hi = -1.0 + (double)(s + 1) * (2.0 / 9.0);
    float t  = (float)((xd - lo) / (hi - lo));
    float t2 = t * t, t3 = t2 * t;
    uint2 r;
    r.x = f2bf(t)  | (f2bf(t2) << 16);
    r.y = f2bf(t3) | ((unsigned int)s << 16);
    return r;
}

// Prepass 1: per (b,i) packed tpow+seg record (8B), layout [B][IN]
__global__ void prep_x_kernel(const float* __restrict__ x, uint2* __restrict__ tp) {
    int idx = blockIdx.x * 256 + threadIdx.x;
    if (idx >= B_DIM * IN_DIM) return;
    tp[idx] = spline_rec_packed(x[idx]);
}

// Prepass 2: coeff -> bf16 (scale folded), TILE-IMAGE order:
// [nt(2)][kt(288)][oct(8)][row(256)][8 bf16] so glds-linear == LDS image.
__global__ void prep_coeff2(const float* __restrict__ c,
                            const float* __restrict__ scale,
                            u32x4* __restrict__ cbf2) {
    int g = blockIdx.x * 256 + threadIdx.x;        // one per 16B granule
    if (g >= (OUT_DIM * KTOT) / 8) return;
    int row = g & 255;
    int oct = (g >> 8) & 7;
    int hi  = g >> 11;                             // nt*288 + kt, 0..575
    int ntg = hi >= 288 ? 1 : 0;
    int kt  = hi - ntg * 288;
    int j = ntg * 256 + row;
    int k = kt * 64 + oct * 8;
    float s = scale[j];
    const float* src = c + (size_t)j * KTOT + k;
    f32x4 a = *(const f32x4*)src;
    f32x4 b = *(const f32x4*)(src + 4);
    u32x4 o;
    o.x = f2bf(a.x * s) | (f2bf(a.y * s) << 16);
    o.y = f2bf(a.z * s) | (f2bf(a.w * s) << 16);
    o.z = f2bf(b.x * s) | (f2bf(b.y * s) << 16);
    o.w = f2bf(b.z * s) | (f2bf(b.w * s) << 16);
    cbf2[g] = o;
}

// scatter 3 candidate records into the staging A tile (own 32-elem half only)
__device__ __forceinline__ void scat3(char* Aq, int ar, int ah,
                                      uint2 q0, uint2 q1, uint2 q2,
                                      int ifirst, int k0) {
#pragma unroll
    for (int cc = 0; cc < 3; ++cc) {
        uint2 rec = cc == 0 ? q0 : (cc == 1 ? q1 : q2);
        int i = ifirst + cc;
        if (i < IN_DIM) {
            int s = (int)(rec.y >> 16);
            int off = i * 36 + s * 4 - k0;                 // multiple of 4; never straddles
            if (off >= 0 && off < 64 && ((off >> 5) == ah)) {
                uint2 w;
                w.x = 0x3F80u | (rec.x << 16);             // {1, t}
                w.y = (rec.x >> 16) | (rec.y << 16);       // {t2, t3}
                *(uint2*)(Aq + (off >> 3) * 4096 + ar * 16 + (off & 4) * 2) = w;
            }
        }
    }
}

#define BAR()   __builtin_amdgcn_s_barrier()
#define SB0()   __builtin_amdgcn_sched_barrier(0)
#define WLGKM() asm volatile("s_waitcnt lgkmcnt(0)" ::: "memory")
#define WVM0()  asm volatile("s_waitcnt vmcnt(0)"   ::: "memory")

// 256x256 tile, 8 waves (2Mx4N), BK=64, 4 phases/K-tile.
// R8: B TRIPLE-buffered (stage t+2 during t) -> the only in-loop VMEM wait is
// the compiler's counted vmcnt before scat3's tp use, which drains B(t+1)
// glds that are a FULL TILE old (m218 counted-wait mechanism). A dbuf.
// LDS = A 2x32KB + B 3x32KB = 160KB (full CU allotment, 1 block/CU).
__launch_bounds__(512, 2)
__global__ void kan_gemm8(const unsigned short* __restrict__ cbf2,
                          const uint2* __restrict__ tp,
                          float* __restrict__ out) {
    __shared__ u32x4 ldsRaw[163840 / 16];          // A:[0,64K) dbuf, B:[64K,160K) tbuf
    char* lds = (char*)ldsRaw;

    const int tid  = threadIdx.x;
    const int lane = tid & 63;
    const int wave = tid >> 6;
    const int wm = wave >> 2, wn = wave & 3;
    const int l15 = lane & 15, lhi = lane >> 4;

    const int bid = blockIdx.x;                    // = mt*16 + ks*2 + nt
    const int mt = bid >> 4;                       // XCD = (2ks+nt)%8: one B panel/XCD
    const int ks = (bid >> 1) & 7;
    const int nt = bid & 1;
    const int m0g = mt * 256, n0g = nt * 256;
    const int kbase = ks * KPER;

    const int ar = tid & 255, ah = tid >> 8;       // staging row / oct-half

    const uint2* tpRow = tp + (size_t)(m0g + ar) * IN_DIM;
    const char*  cbase = (const char*)cbf2 + (size_t)(nt * 288 + ks * NT8) * 32768;

    const int aoff = (wm * 128 + l15) * 16;        // A frag row byte offset
    const int boff = (wn * 64  + l15) * 16;        // B frag row byte offset
    const int ohi  = lhi * 4096;

    f32x4 acc[8][4] = {};
    s16x8 av[4], bv[4];
    uint2 r0, r1, r2;

    // ---------------- prologue: A(0), B(0), B(1); recs for A(1) ----------------
    {
        char* A0 = lds;
        const int if0 = kbase / 36;
        r0 = tpRow[if0];
        r1 = tpRow[if0 + 1 < IN_DIM ? if0 + 1 : IN_DIM - 1];
        r2 = tpRow[if0 + 2 < IN_DIM ? if0 + 2 : IN_DIM - 1];
        u32x4 z = {};
#pragma unroll
        for (int zi = 0; zi < 4; ++zi)
            *(u32x4*)(A0 + (ah * 4 + zi) * 4096 + ar * 16) = z;
        scat3(A0, ar, ah, r0, r1, r2, if0, kbase);
#pragma unroll
        for (int it = 0; it < 4; ++it)              // B(0) -> buf0
            glds16(cbase + it * 8192 + tid * 16, lds + 65536 + it * 8192 + tid * 16);
#pragma unroll
        for (int it = 0; it < 4; ++it)              // B(1) -> buf1
            glds16(cbase + 32768 + it * 8192 + tid * 16,
                   lds + 98304 + it * 8192 + tid * 16);
        const int if1 = (kbase + BK) / 36;          // records for A(1)'s scatter
        r0 = tpRow[if1];
        r1 = tpRow[if1 + 1 < IN_DIM ? if1 + 1 : IN_DIM - 1];
        r2 = tpRow[if1 + 2 < IN_DIM ? if1 + 2 : IN_DIM - 1];
        WVM0();                                     // prologue-only full drain
        WLGKM();
        BAR();
        SB0();
    }

#define LOAD_A(KH, MH)                                                          \
    _Pragma("unroll") for (int c_ = 0; c_ < 4; ++c_)                            \
        av[c_] = *(const s16x8*)(Ap + (KH) * 16384 + ohi + aoff + ((MH) * 4 + c_) * 256);
#define LOAD_B(KH)                                                              \
    _Pragma("unroll") for (int c_ = 0; c_ < 4; ++c_)                            \
        bv[c_] = *(const s16x8*)(Bp + (KH) * 16384 + ohi + boff + c_ * 256);
#define MFMA_Q(MH)                                                              \
    _Pragma("unroll") for (int mf_ = 0; mf_ < 4; ++mf_)                         \
        _Pragma("unroll") for (int nf_ = 0; nf_ < 4; ++nf_)                     \
            acc[(MH) * 4 + mf_][nf_] = __builtin_amdgcn_mfma_f32_16x16x32_bf16( \
                av[mf_], bv[nf_], acc[(MH) * 4 + mf_][nf_], 0, 0, 0);
#define PHASE_MID() BAR(); WLGKM(); SB0(); __builtin_amdgcn_s_setprio(1)
#define PHASE_END() __builtin_amdgcn_s_setprio(0); BAR()

    int bcur = 0, bstg = 2;                        // B(t) buf, B(t+2) buf (mod 3)
    for (int t = 0; t < NT8; ++t) {
        const int p = t & 1;
        const char* Ap = lds + p * 32768;
        char* Aq = lds + (p ^ 1) * 32768;
        const char* Bp = lds + 65536 + bcur * 32768;
        char* Bs = lds + 65536 + bstg * 32768;     // staging dest for B(t+2)
        const int tt1 = t + 1 < NT8 ? t + 1 : NT8 - 1;
        const int tt2 = t + 2 < NT8 ? t + 2 : NT8 - 1;
        const int k0n = kbase + tt1 * BK;
        const char* srcT = cbase + (size_t)tt2 * 32768;   // B(t+2) source
        u32x4 z = {};

        // ---- phase 0: kh0, m-half 0; zero oct0-1(A t+1); glds#0 (B t+2) ----
        LOAD_B(0); LOAD_A(0, 0);
        *(u32x4*)(Aq + (ah * 4 + 0) * 4096 + ar * 16) = z;
        *(u32x4*)(Aq + (ah * 4 + 1) * 4096 + ar * 16) = z;
        glds16(srcT + 0 * 8192 + tid * 16, Bs + 0 * 8192 + tid * 16);
        PHASE_MID(); MFMA_Q(0); PHASE_END();

        // ---- phase 1: kh0, m-half 1; zero oct2-3; glds#1 ----
        LOAD_A(0, 1);
        *(u32x4*)(Aq + (ah * 4 + 2) * 4096 + ar * 16) = z;
        *(u32x4*)(Aq + (ah * 4 + 3) * 4096 + ar * 16) = z;
        glds16(srcT + 1 * 8192 + tid * 16, Bs + 1 * 8192 + tid * 16);
        PHASE_MID(); MFMA_Q(1); PHASE_END();

        // ---- phase 2: kh1, m-half 0; glds#2 ----
        LOAD_B(1); LOAD_A(1, 0);
        glds16(srcT + 2 * 8192 + tid * 16, Bs + 2 * 8192 + tid * 16);
        PHASE_MID(); MFMA_Q(0); PHASE_END();

        // ---- phase 3: kh1, m-half 1; scatter (its compiler vmcnt wait drains
        //      the FULL-TILE-OLD B(t+1) glds); glds#3; tp prefetch ----
        LOAD_A(1, 1);
        {
            const int if1 = k0n / 36;
            scat3(Aq, ar, ah, r0, r1, r2, if1, k0n);
        }
        glds16(srcT + 3 * 8192 + tid * 16, Bs + 3 * 8192 + tid * 16);
        {
            const int if2 = (kbase + tt2 * BK) / 36;   // recs for A(t+2): in flight
            r0 = tpRow[if2];                           // across the tile boundary
            r1 = tpRow[if2 + 1 < IN_DIM ? if2 + 1 : IN_DIM - 1];
            r2 = tpRow[if2 + 2 < IN_DIM ? if2 + 2 : IN_DIM - 1];
        }
        PHASE_MID(); MFMA_Q(1); PHASE_END();

        bcur = bcur == 2 ? 0 : bcur + 1;
        bstg = bstg == 2 ? 0 : bstg + 1;
    }

    // ---- epilogue: split-K atomics. C/D: col=lane&15 (n), row=(lane>>4)*4+e (m) ----
#pragma unroll
    for (int mf = 0; mf < 8; ++mf) {
        const int rg = m0g + wm * 128 + mf * 16 + lhi * 4;
#pragma unroll
        for (int nf = 0; nf < 4; ++nf) {
            const int cg = n0g + wn * 64 + nf * 16 + l15;
#pragma unroll
            for (int e = 0; e < 4; ++e)
                atomicAdd(out + (size_t)(rg + e) * OUT_DIM + cg, acc[mf][nf][e]);
        }
    }
}

// ---------------- fallback (no workspace): round-1 proven kernel ----------------
#define BM 128
#define BN 128
#define FBK 64
#define FKPER  4608
#define FSTEPS 72
__launch_bounds__(256, 2)
__global__ void kan_gemm_ref(const float* __restrict__ x,
                             const float* __restrict__ coeff,
                             const float* __restrict__ scale,
                             float* __restrict__ out) {
    __shared__ unsigned short AsF[BM * 72];
    __shared__ unsigned short BsF[8 * BN * 8];
    const int tid  = threadIdx.x;
    const int lane = tid & 63;
    const int wave = tid >> 6;
    const int wm = wave >> 1, wn = wave & 1;
    const int l15 = lane & 15, lhi = lane >> 4;
    const int bid = blockIdx.x;
    const int nt = bid & 3;
    const int ks = (bid >> 2) & 3;
    const int mt = bid >> 4;
    const int m0g = mt * BM, n0g = nt * BN, kbase = ks * FKPER;
    const int ar = tid >> 1, ah = tid & 1;
    const int abrow = m0g + ar;
    const int bjg = n0g + (tid & 127);
    const float bscale = scale[bjg];
    char* AsB = (char*)AsF;
    char* BsB = (char*)BsF;
    f32x4 acc[4][4] = {};
    for (int step = 0; step < FSTEPS; ++step) {
        const int k0 = kbase + step * FBK;
        {
            char* rb = AsB + ar * 144;
            u32x4 z = {};
            if (ah == 0) {
#pragma unroll
                for (int z4 = 0; z4 < 4; ++z4) *(u32x4*)(rb + z4 * 16) = z;
            } else {
#pragma unroll
                for (int z4 = 4; z4 < 9; ++z4) *(u32x4*)(rb + z4 * 16) = z;
            }
            const int ifirst = k0 / 36;
#pragma unroll
            for (int ii = 0; ii < 2; ++ii) {
                const int cand = ah + ii * 2;
                const int i = ifirst + cand;
                if (cand < 3 && i * 36 < k0 + FBK && i < IN_DIM) {
                    uint2 rec = spline_rec_packed(x[(size_t)abrow * IN_DIM + i]);
                    int s = (int)(rec.y >> 16);
                    const int off = i * 36 + s * 4 - k0;
                    unsigned int w0 = 0x3F80u | (rec.x << 16);
                    unsigned int w1 = (rec.x >> 16) | (rec.y << 16);
                    if (off >= 0 && off <= 62) *(unsigned int*)(rb + off * 2) = w0;
                    const int off2 = off + 2;
                    if (off2 >= 0 && off2 <= 62) *(unsigned int*)(rb + off2 * 2) = w1;
                }
            }
        }
#pragma unroll
        for (int it = 0; it < 4; ++it) {
            const int q  = it * 256 + tid;
            const int c  = q >> 7;
            const int kk = k0 + c * 8;
            f32x4 a = *(const f32x4*)(coeff + (size_t)bjg * KTOT + kk);
            f32x4 b = *(const f32x4*)(coeff + (size_t)bjg * KTOT + kk + 4);
            u32x4 o;
            o.x = f2bf(a.x * bscale) | (f2bf(a.y * bscale) << 16);
            o.y = f2bf(a.z * bscale) | (f2bf(a.w * bscale) << 16);
            o.z = f2bf(b.x * bscale) | (f2bf(b.y * bscale) << 16);
            o.w = f2bf(b.z * bscale) | (f2bf(b.w * bscale) << 16);
            *(u32x4*)(BsB + q * 16) = o;
        }
        __syncthreads();
#pragma unroll
        for (int kh = 0; kh < 2; ++kh) {
            const int kk = kh * 32;
            s16x8 a[4], b[4];
#pragma unroll
            for (int mf = 0; mf < 4; ++mf)
                a[mf] = *(const s16x8*)(AsB + (wm * 64 + mf * 16 + l15) * 144 + (kk + lhi * 8) * 2);
#pragma unroll
            for (int nf = 0; nf < 4; ++nf)
                b[nf] = *(const s16x8*)(BsB + (kh * 4 + lhi) * 2048 + (wn * 64 + nf * 16 + l15) * 16);
#pragma unroll
            for (int mf = 0; mf < 4; ++mf)
#pragma unroll
                for (int nf = 0; nf < 4; ++nf)
                    acc[mf][nf] = __builtin_amdgcn_mfma_f32_16x16x32_bf16(a[mf], b[nf], acc[mf][nf], 0, 0, 0);
        }
        __syncthreads();
    }
#pragma unroll
    for (int mf = 0; mf < 4; ++mf) {
        const int cmBase = m0g + wm * 64 + mf * 16 + lhi * 4;
#pragma unroll
        for (int nf = 0; nf < 4; ++nf) {
            const int cn = n0g + wn * 64 + nf * 16 + l15;
#pragma unroll
            for (int e = 0; e < 4; ++e)
                atomicAdd(out + (size_t)(cmBase + e) * OUT_DIM + cn, acc[mf][nf][e]);
        }
    }
}

extern "C" void kernel_launch(void* const* d_in, const int* in_sizes, int n_in,
                              void* d_out, int out_size, void* d_ws, size_t ws_size,
                              hipStream_t stream) {
    const float* x     = (const float*)d_in[0];
    const float* coeff = (const float*)d_in[1];
    const float* scale = (const float*)d_in[2];
    float* out = (float*)d_out;

    const size_t SZ_CBF = (size_t)OUT_DIM * KTOT * 2;   // 18,874,368
    const size_t SZ_TP  = (size_t)B_DIM * IN_DIM * 8;   // 16,777,216
    const size_t NEED   = SZ_CBF + SZ_TP;               // ~35.7 MB

    hipMemsetAsync(d_out, 0, (size_t)B_DIM * OUT_DIM * sizeof(float), stream);

    if (ws_size >= NEED) {
        unsigned short* cbf2 = (unsigned short*)d_ws;
        uint2*          tp   = (uint2*)((char*)d_ws + SZ_CBF);
        prep_coeff2<<<4608, 256, 0, stream>>>(coeff, scale, (u32x4*)cbf2);
        prep_x_kernel<<<8192, 256, 0, stream>>>(x, tp);
        kan_gemm8<<<256, 512, 0, stream>>>(cbf2, tp, out);
    } else {
        kan_gemm_ref<<<512, 256, 0, stream>>>(x, coeff, scale, out);
    }
}